// Round 14
// baseline (1180.913 us; speedup 1.0000x reference)
//
#include <hip/hip_runtime.h>

typedef unsigned short u16;
typedef unsigned int u32;
typedef __attribute__((ext_vector_type(8))) short s8v;   // 8 bf16 = 4 VGPR
typedef __attribute__((ext_vector_type(4))) float f4v;   // MFMA accum

#define SCAN_B 240

// ---------- bf16 helpers ----------
__device__ __forceinline__ u16 f2bf(float f) {
  u32 u = __float_as_uint(f);
  u += 0x7FFFu + ((u >> 16) & 1u);
  return (u16)(u >> 16);
}
__device__ __forceinline__ void unp2(u32 u, float& a, float& b) {
  a = __uint_as_float(u << 16);
  b = __uint_as_float(u & 0xFFFF0000u);
}
__device__ __forceinline__ u32 pk2(float a, float b) {
  return (u32)f2bf(a) | ((u32)f2bf(b) << 16);
}

// ---------- init: f32 copy + bf16 shadow + zero CSR counters, one dispatch ----------
__global__ void k_init2(const float* __restrict__ lsrc, float* __restrict__ ld32,
                        u16* __restrict__ ldbf,
                        const float* __restrict__ csrc, float* __restrict__ cd32,
                        u16* __restrict__ cdbf, int nl, int nc,
                        int* __restrict__ cntL, int nzL, int* __restrict__ cntC, int nzC) {
  int i = blockIdx.x * blockDim.x + threadIdx.x, st = gridDim.x * blockDim.x;
  int tot = nl + nc + nzL + nzC;
  for (; i < tot; i += st) {
    if (i < nl) { float v = lsrc[i]; ld32[i] = v; ldbf[i] = f2bf(v); }
    else if (i < nl + nc) { int j = i - nl; float v = csrc[j]; cd32[j] = v; cdbf[j] = f2bf(v); }
    else if (i < nl + nc + nzL) cntL[i - nl - nc] = 0;
    else cntC[i - nl - nc - nzL] = 0;
  }
}

// ---------- CSR build ----------
__global__ void k_hist2(const int* __restrict__ l_edge, int* __restrict__ cntL,
                        const int* __restrict__ c_edge, int* __restrict__ cntC, int ne) {
  int i = blockIdx.x * blockDim.x + threadIdx.x, s = gridDim.x * blockDim.x;
  for (; i < 2 * ne; i += s) {
    if (i < ne) atomicAdd(&cntL[l_edge[i]], 1);
    else atomicAdd(&cntC[c_edge[i - ne]], 1);
  }
}
__global__ __launch_bounds__(256) void k_scanA(const int* __restrict__ cntL, int nL,
                                               const int* __restrict__ cntC, int nC,
                                               int* __restrict__ bsums) {
  const bool isL = (int)blockIdx.x < SCAN_B;
  const int* cnt = isL ? cntL : cntC;
  const int n = isL ? nL : nC;
  const int b = isL ? blockIdx.x : blockIdx.x - SCAN_B;
  const int chunk = (n + SCAN_B - 1) / SCAN_B;
  const int s0 = b * chunk;
  int s1 = s0 + chunk; if (s1 > n) s1 = n;
  int s = 0;
  for (int i = s0 + (int)threadIdx.x; i < s1; i += 256) s += cnt[i];
  __shared__ int red[256];
  red[threadIdx.x] = s; __syncthreads();
  for (int d = 128; d >= 1; d >>= 1) {
    if ((int)threadIdx.x < d) red[threadIdx.x] += red[threadIdx.x + d];
    __syncthreads();
  }
  if (threadIdx.x == 0) bsums[blockIdx.x] = red[0];
}
// scanC with folded block-sum scan (replaces the former k_scanB dispatch)
__global__ __launch_bounds__(256) void k_scanC(int* __restrict__ cntL, int* __restrict__ offL, int nL,
                                               int* __restrict__ cntC, int* __restrict__ offC, int nC,
                                               const int* __restrict__ bsums) {
  const bool isL = (int)blockIdx.x < SCAN_B;
  int* cnt = isL ? cntL : cntC;
  int* offs = isL ? offL : offC;
  const int n = isL ? nL : nC;
  const int b = isL ? blockIdx.x : blockIdx.x - SCAN_B;
  const int* bs = bsums + (isL ? 0 : SCAN_B);
  const int t = threadIdx.x;
  __shared__ int shb[256];
  int bv = (t < SCAN_B) ? bs[t] : 0;
  shb[t] = bv; __syncthreads();
  for (int d = 1; d < 256; d <<= 1) {
    int x = (t >= d) ? shb[t - d] : 0;
    __syncthreads();
    shb[t] += x;
    __syncthreads();
  }
  int run = (b == 0) ? 0 : shb[b - 1];
  const int total = shb[255];
  const int chunk = (n + SCAN_B - 1) / SCAN_B;
  const int s0 = b * chunk;
  int s1 = s0 + chunk; if (s1 > n) s1 = n;
  __shared__ int sh[256];
  for (int t0 = s0; t0 < s1; t0 += 256) {
    int i = t0 + t;
    int v = (i < s1) ? cnt[i] : 0;
    sh[t] = v; __syncthreads();
    for (int d = 1; d < 256; d <<= 1) {
      int x = (t >= d) ? sh[t - d] : 0;
      __syncthreads();
      sh[t] += x;
      __syncthreads();
    }
    int incl = sh[t];
    if (i < s1) { int e = run + incl - v; offs[i] = e; cnt[i] = e; }
    int tilesum = sh[255];
    __syncthreads();
    run += tilesum;
  }
  if (b == 0 && t == 0) offs[n] = total;
}
__global__ void k_fill_l(const int* __restrict__ l_edge, const int* __restrict__ c_edge,
                         int* __restrict__ cursor, int* __restrict__ l_src,
                         int* __restrict__ l_posmap, int ne) {
  int i = blockIdx.x * blockDim.x + threadIdx.x, s = gridDim.x * blockDim.x;
  for (; i < ne; i += s) {
    int pos = atomicAdd(&cursor[l_edge[i]], 1);
    l_src[pos] = c_edge[i];
    l_posmap[i] = pos;
  }
}
__global__ void k_fill_c(const int* __restrict__ l_edge, const int* __restrict__ c_edge,
                         const int* __restrict__ l_posmap,
                         int* __restrict__ cursor, int* __restrict__ c_src,
                         int* __restrict__ c_lpos, int ne) {
  int i = blockIdx.x * blockDim.x + threadIdx.x, s = gridDim.x * blockDim.x;
  for (; i < ne; i += s) {
    int pos = atomicAdd(&cursor[c_edge[i]], 1);
    c_src[pos] = l_edge[i];
    c_lpos[pos] = l_posmap[i];
  }
}

// ---------- weight repack: f32 [K][128] -> bf16 MFMA B-frag layout ----------
__global__ void k_packW(const float* __restrict__ l2c_W, const float* __restrict__ c2l_W,
                        const float* __restrict__ l2l_W, const float* __restrict__ c_upd_W,
                        const float* __restrict__ l_upd_W, u16* __restrict__ dst, int total) {
  int o = blockIdx.x * blockDim.x + threadIdx.x;
  if (o >= total) return;
  int it = o / 180224;
  int r = o - it * 180224;
  const float* src;
  int o2;
  if (r < 98304) {
    int m = r >> 14;           // 0..5
    o2 = r & 16383;
    if (m < 2)      src = l2c_W + ((size_t)it * 2 + m) * 16384;
    else if (m < 4) src = c2l_W + ((size_t)it * 2 + (m - 2)) * 16384;
    else            src = l2l_W + ((size_t)it * 2 + (m - 4)) * 16384;
  } else if (r < 131072) {
    o2 = r - 98304;  src = c_upd_W + (size_t)it * 32768;
  } else {
    o2 = r - 131072; src = l_upd_W + (size_t)it * 49152;
  }
  int j = o2 & 7, lane = (o2 >> 3) & 63, f = o2 >> 9;
  int nt = f & 7, kc = f >> 3;
  int k = kc * 32 + ((lane >> 4) << 3) + j;
  int nn = nt * 16 + (lane & 15);
  dst[o] = f2bf(src[(size_t)k * 128 + nn]);
}

// ---------- phase 1: merged L-side dual-MLP + C-side MLP (+ fused dots) ----------
// Staging-free, barrier-free: A-frags direct from global (coalesced 16B/lane);
// hs is wave-private (each wave's D rows == its next-layer A rows).
__global__ __launch_bounds__(256) void k_phase1(
    const u16* __restrict__ cl_bf, const u16* __restrict__ cc_bf,
    const u16* __restrict__ pl2c0, const float* __restrict__ bl0,
    const u16* __restrict__ pl2c1, const float* __restrict__ bl1,
    const u16* __restrict__ pl2l0, const float* __restrict__ bx0,
    const u16* __restrict__ pl2l1, const float* __restrict__ bx1,
    u16* __restrict__ lbuf, u16* __restrict__ lmsg2,
    const float* __restrict__ lattA, const float* __restrict__ cattB,
    float* __restrict__ lab,
    const u16* __restrict__ pc2l0, const float* __restrict__ bc0,
    const u16* __restrict__ pc2l1, const float* __restrict__ bc1,
    u16* __restrict__ cmsg,
    const float* __restrict__ cattA, const float* __restrict__ lattB,
    float* __restrict__ ca, float* __restrict__ cb,
    int L, int C, int NBL)
{
  __shared__ u16 hs[64][136];
  const int tid = threadIdx.x;
  const int lane = tid & 63;
  const int w = tid >> 6;
  const bool isL = (int)blockIdx.x < NBL;
  const int r0 = (isL ? blockIdx.x : blockIdx.x - NBL) * 64;
  const int n = isL ? L : C;
  const u16* x_bf = isL ? cl_bf : cc_bf;
  const u16* pW0 = isL ? pl2c0 : pc2l0;
  const float* b0 = isL ? bl0 : bc0;
  const u16* pW1 = isL ? pl2c1 : pc2l1;
  const float* b1 = isL ? bl1 : bc1;
  u16* y = isL ? lbuf : cmsg;
  const float* attx = isL ? lattA : cattA;
  const float* atty = isL ? cattB : lattB;
  float* dx = isL ? lab : ca;        // x-dot target
  float* dy = isL ? lab + 1 : cb;    // y-dot target
  const int dstr = isL ? 2 : 1;

  const int wr0 = w * 16;

  // fused x-dot (direct global reads, per-row wave reduce)
  {
    float2 ax = *(const float2*)(attx + lane * 2);
    for (int r = 0; r < 16; ++r) {
      int gr = r0 + wr0 + r;
      if (gr >= n) break;
      u32 v = *(const u32*)(x_bf + (size_t)gr * 128 + lane * 2);
      float f0, f1; unp2(v, f0, f1);
      float p = f0 * ax.x + f1 * ax.y;
#pragma unroll
      for (int d = 32; d >= 1; d >>= 1) p += __shfl_xor(p, d);
      if (lane == 0) dx[(size_t)gr * dstr] = p;
    }
  }

  const int arowg = r0 + wr0 + (lane & 15);   // global A row
  const bool okA = arowg < n;
  const int kgrp = (lane >> 4) * 8;
  const int dcol = lane & 15;
  const int lrow = wr0 + (lane & 15);         // block-local hs A row
  const int drow0 = wr0 + ((lane >> 4) << 2); // block-local hs D row base
  const s8v zero = {0, 0, 0, 0, 0, 0, 0, 0};
  f4v acc[8];

  // ----- MLP1 layer 0 (A direct from global) -----
#pragma unroll
  for (int nt = 0; nt < 8; ++nt) {
    float bv = b0[nt * 16 + dcol];
    acc[nt] = (f4v){bv, bv, bv, bv};
  }
#pragma unroll
  for (int kc = 0; kc < 4; ++kc) {
    s8v a = okA ? *(const s8v*)(x_bf + (size_t)arowg * 128 + kc * 32 + kgrp) : zero;
#pragma unroll
    for (int nt = 0; nt < 8; ++nt) {
      s8v b = *(const s8v*)(pW0 + ((size_t)(kc * 8 + nt) * 64 + lane) * 8);
      acc[nt] = __builtin_amdgcn_mfma_f32_16x16x32_bf16(a, b, acc[nt], 0, 0, 0);
    }
  }
#pragma unroll
  for (int nt = 0; nt < 8; ++nt)
#pragma unroll
    for (int r = 0; r < 4; ++r)
      hs[drow0 + r][nt * 16 + dcol] = f2bf(fmaxf(acc[nt][r], 0.f));
  // ----- MLP1 layer 1 (hs wave-private: no barrier) -----
#pragma unroll
  for (int nt = 0; nt < 8; ++nt) {
    float bv = b1[nt * 16 + dcol];
    acc[nt] = (f4v){bv, bv, bv, bv};
  }
#pragma unroll
  for (int kc = 0; kc < 4; ++kc) {
    s8v a = *(const s8v*)&hs[lrow][kc * 32 + kgrp];
#pragma unroll
    for (int nt = 0; nt < 8; ++nt) {
      s8v b = *(const s8v*)(pW1 + ((size_t)(kc * 8 + nt) * 64 + lane) * 8);
      acc[nt] = __builtin_amdgcn_mfma_f32_16x16x32_bf16(a, b, acc[nt], 0, 0, 0);
    }
  }
#pragma unroll
  for (int nt = 0; nt < 8; ++nt)
#pragma unroll
    for (int r = 0; r < 4; ++r) {
      int gr = r0 + drow0 + r;
      if (gr < n) y[(size_t)gr * 128 + nt * 16 + dcol] = f2bf(acc[nt][r]);
    }
  // fused y-dot
  {
    float pr[4] = {0.f, 0.f, 0.f, 0.f};
#pragma unroll
    for (int nt = 0; nt < 8; ++nt) {
      float av = atty[nt * 16 + dcol];
#pragma unroll
      for (int r = 0; r < 4; ++r) pr[r] = fmaf(acc[nt][r], av, pr[r]);
    }
#pragma unroll
    for (int d = 8; d >= 1; d >>= 1)
#pragma unroll
      for (int r = 0; r < 4; ++r) pr[r] += __shfl_xor(pr[r], d);
    if ((lane & 15) == 0) {
#pragma unroll
      for (int r = 0; r < 4; ++r) {
        int gr = r0 + drow0 + r;
        if (gr < n) dy[(size_t)gr * dstr] = pr[r];
      }
    }
  }

  // ----- MLP2 (L-side only; hs reuse is wave-private -> no barrier) -----
  if (isL) {
#pragma unroll
    for (int nt = 0; nt < 8; ++nt) {
      float bv = bx0[nt * 16 + dcol];
      acc[nt] = (f4v){bv, bv, bv, bv};
    }
#pragma unroll
    for (int kc = 0; kc < 4; ++kc) {
      s8v a = okA ? *(const s8v*)(x_bf + (size_t)arowg * 128 + kc * 32 + kgrp) : zero;
#pragma unroll
      for (int nt = 0; nt < 8; ++nt) {
        s8v b = *(const s8v*)(pl2l0 + ((size_t)(kc * 8 + nt) * 64 + lane) * 8);
        acc[nt] = __builtin_amdgcn_mfma_f32_16x16x32_bf16(a, b, acc[nt], 0, 0, 0);
      }
    }
#pragma unroll
    for (int nt = 0; nt < 8; ++nt)
#pragma unroll
      for (int r = 0; r < 4; ++r)
        hs[drow0 + r][nt * 16 + dcol] = f2bf(fmaxf(acc[nt][r], 0.f));
#pragma unroll
    for (int nt = 0; nt < 8; ++nt) {
      float bv = bx1[nt * 16 + dcol];
      acc[nt] = (f4v){bv, bv, bv, bv};
    }
#pragma unroll
    for (int kc = 0; kc < 4; ++kc) {
      s8v a = *(const s8v*)&hs[lrow][kc * 32 + kgrp];
#pragma unroll
      for (int nt = 0; nt < 8; ++nt) {
        s8v b = *(const s8v*)(pl2l1 + ((size_t)(kc * 8 + nt) * 64 + lane) * 8);
        acc[nt] = __builtin_amdgcn_mfma_f32_16x16x32_bf16(a, b, acc[nt], 0, 0, 0);
      }
    }
#pragma unroll
    for (int nt = 0; nt < 8; ++nt)
#pragma unroll
      for (int r = 0; r < 4; ++r) {
        int gr = r0 + drow0 + r;
        if (gr < n) lmsg2[(size_t)gr * 128 + nt * 16 + dcol] = f2bf(acc[nt][r]);
      }
  }
}

// ---------- phase 2: fused softmax + clause aggregation (wave per clause) ----------
__global__ __launch_bounds__(256) void k_att_aggrC(
    const int* __restrict__ c_off, const int* __restrict__ c_src, const int* __restrict__ c_lpos,
    const float* __restrict__ ca, const float* __restrict__ cb,
    const float2* __restrict__ lab,
    float* __restrict__ w2p,
    const u32* __restrict__ feat32, u32* __restrict__ out32, int C)
{
  const int lane = threadIdx.x & 63;
  const int gid = blockIdx.x * 4 + (threadIdx.x >> 6);
  if (gid >= C) return;
  const int off = c_off[gid];
  const int deg = c_off[gid + 1] - off;
  float a0 = 0.f, a1 = 0.f;
  if (deg > 0 && deg <= 64) {
    const float cav = ca[gid], cbv = cb[gid];
    bool on = lane < deg;
    int sv = 0, lp = 0;
    float s1 = -3.0e38f, s2 = -3.0e38f;
    if (on) {
      sv = c_src[off + lane];
      lp = c_lpos[off + lane];
      float2 v = lab[sv];            // .x = lb (x-dot), .y = la (y-dot)
      s1 = cav + v.y; s1 = s1 > 0.f ? s1 : 0.2f * s1;
      s2 = v.x + cbv; s2 = s2 > 0.f ? s2 : 0.2f * s2;
    }
    float m1 = s1, m2 = s2;
#pragma unroll
    for (int d = 32; d >= 1; d >>= 1) {
      m1 = fmaxf(m1, __shfl_xor(m1, d));
      m2 = fmaxf(m2, __shfl_xor(m2, d));
    }
    float e1 = on ? __expf(s1 - m1) : 0.f;
    float e2 = on ? __expf(s2 - m2) : 0.f;
    float z1 = e1, z2 = e2;
#pragma unroll
    for (int d = 32; d >= 1; d >>= 1) {
      z1 += __shfl_xor(z1, d);
      z2 += __shfl_xor(z2, d);
    }
    float wv = on ? e1 / (z1 + 1e-16f) : 0.f;
    if (on) w2p[lp] = e2 / (z2 + 1e-16f);
    int j = 0;
    for (; j + 4 <= deg; j += 4) {
      int s0 = __shfl(sv, j), s1i = __shfl(sv, j + 1), s2i = __shfl(sv, j + 2), s3i = __shfl(sv, j + 3);
      float w0 = __shfl(wv, j), w1i = __shfl(wv, j + 1), w2i = __shfl(wv, j + 2), w3i = __shfl(wv, j + 3);
      u32 d0 = feat32[(size_t)s0 * 64 + lane];
      u32 d1 = feat32[(size_t)s1i * 64 + lane];
      u32 d2 = feat32[(size_t)s2i * 64 + lane];
      u32 d3 = feat32[(size_t)s3i * 64 + lane];
      float f0, f1;
      unp2(d0, f0, f1); a0 = fmaf(w0, f0, a0); a1 = fmaf(w0, f1, a1);
      unp2(d1, f0, f1); a0 = fmaf(w1i, f0, a0); a1 = fmaf(w1i, f1, a1);
      unp2(d2, f0, f1); a0 = fmaf(w2i, f0, a0); a1 = fmaf(w2i, f1, a1);
      unp2(d3, f0, f1); a0 = fmaf(w3i, f0, a0); a1 = fmaf(w3i, f1, a1);
    }
    for (; j < deg; ++j) {
      int sj = __shfl(sv, j); float wj = __shfl(wv, j);
      u32 d = feat32[(size_t)sj * 64 + lane];
      float f0, f1; unp2(d, f0, f1);
      a0 = fmaf(wj, f0, a0); a1 = fmaf(wj, f1, a1);
    }
  } else if (deg > 64) {
    const float cav = ca[gid], cbv = cb[gid];
    float m1 = -3.0e38f, m2 = -3.0e38f;
    for (int base = 0; base < deg; base += 64) {
      int idx = base + lane;
      if (idx < deg) {
        float2 v = lab[c_src[off + idx]];
        float s1 = cav + v.y; s1 = s1 > 0.f ? s1 : 0.2f * s1;
        float s2 = v.x + cbv; s2 = s2 > 0.f ? s2 : 0.2f * s2;
        m1 = fmaxf(m1, s1); m2 = fmaxf(m2, s2);
      }
    }
#pragma unroll
    for (int d = 32; d >= 1; d >>= 1) {
      m1 = fmaxf(m1, __shfl_xor(m1, d));
      m2 = fmaxf(m2, __shfl_xor(m2, d));
    }
    float z1 = 0.f, z2 = 0.f;
    for (int base = 0; base < deg; base += 64) {
      int idx = base + lane;
      if (idx < deg) {
        float2 v = lab[c_src[off + idx]];
        float s1 = cav + v.y; s1 = s1 > 0.f ? s1 : 0.2f * s1;
        float s2 = v.x + cbv; s2 = s2 > 0.f ? s2 : 0.2f * s2;
        z1 += __expf(s1 - m1); z2 += __expf(s2 - m2);
      }
    }
#pragma unroll
    for (int d = 32; d >= 1; d >>= 1) { z1 += __shfl_xor(z1, d); z2 += __shfl_xor(z2, d); }
    float i1 = 1.f / (z1 + 1e-16f), i2 = 1.f / (z2 + 1e-16f);
    for (int base = 0; base < deg; base += 64) {
      int m = deg - base; if (m > 64) m = 64;
      int sv = 0; float wv = 0.f;
      if (lane < m) {
        int idx = base + lane;
        sv = c_src[off + idx];
        float2 v = lab[sv];
        float s1 = cav + v.y; s1 = s1 > 0.f ? s1 : 0.2f * s1;
        float s2 = v.x + cbv; s2 = s2 > 0.f ? s2 : 0.2f * s2;
        wv = __expf(s1 - m1) * i1;
        w2p[c_lpos[off + idx]] = __expf(s2 - m2) * i2;
      }
      for (int j = 0; j < m; ++j) {
        int sj = __shfl(sv, j); float wj = __shfl(wv, j);
        u32 d = feat32[(size_t)sj * 64 + lane];
        float f0, f1; unp2(d, f0, f1);
        a0 = fmaf(wj, f0, a0); a1 = fmaf(wj, f1, a1);
      }
    }
  }
  out32[(size_t)gid * 64 + lane] = pk2(a0, a1);
}

// ---------- phase 3: merged clause update GEMM (LDS-free) + literal aggregation ----------
__global__ __launch_bounds__(256) void k_phase3(
    const u16* __restrict__ cc_bf, const u16* __restrict__ cagg,
    const u16* __restrict__ pWc, const float* __restrict__ biasC,
    float* __restrict__ obC, u16* __restrict__ obC_bf, int C, int UBC,
    const int* __restrict__ l_off, const float* __restrict__ w2p,
    const int* __restrict__ l_src,
    const u32* __restrict__ cmsg32, u32* __restrict__ lagg32, int L)
{
  const int tid = threadIdx.x;
  const int lane = tid & 63;
  const int w = tid >> 6;
  if ((int)blockIdx.x < UBC) {
    const int r0 = blockIdx.x * 64;
    const int arow = r0 + w * 16 + (lane & 15);
    const int kgrp = (lane >> 4) * 8;
    const int dcol = lane & 15;
    const int drow0 = w * 16 + (lane >> 4) * 4;
    const bool ok = arow < C;
    f4v acc[8];
#pragma unroll
    for (int nt = 0; nt < 8; ++nt) {
      float bv = biasC[nt * 16 + dcol];
      acc[nt] = (f4v){bv, bv, bv, bv};
    }
#pragma unroll
    for (int kc = 0; kc < 8; ++kc) {
      int col = kc * 32 + kgrp;
      s8v a = {0, 0, 0, 0, 0, 0, 0, 0};
      if (ok) {
        if (kc < 4) a = *(const s8v*)(cc_bf + (size_t)arow * 128 + col);
        else        a = *(const s8v*)(cagg + (size_t)arow * 128 + (col - 128));
      }
#pragma unroll
      for (int nt = 0; nt < 8; ++nt) {
        s8v b = *(const s8v*)(pWc + ((size_t)(kc * 8 + nt) * 64 + lane) * 8);
        acc[nt] = __builtin_amdgcn_mfma_f32_16x16x32_bf16(a, b, acc[nt], 0, 0, 0);
      }
    }
#pragma unroll
    for (int nt = 0; nt < 8; ++nt)
#pragma unroll
      for (int r = 0; r < 4; ++r) {
        int gr = r0 + drow0 + r;
        if (gr < C) {
          float v = acc[nt][r];
          obC[(size_t)gr * 128 + nt * 16 + dcol] = v;
          obC_bf[(size_t)gr * 128 + nt * 16 + dcol] = f2bf(v);
        }
      }
  } else {
    const int seg = (blockIdx.x - UBC) * 4 + w;
    if (seg >= L) return;
    const int off = l_off[seg];
    const int deg = l_off[seg + 1] - off;
    float a0 = 0.f, a1 = 0.f;
    for (int base = 0; base < deg; base += 64) {
      int m = deg - base; if (m > 64) m = 64;
      float wv = 0.f; int sv = 0;
      if (lane < m) { wv = w2p[off + base + lane]; sv = l_src[off + base + lane]; }
      int j = 0;
      for (; j + 4 <= m; j += 4) {
        int s0 = __shfl(sv, j), s1i = __shfl(sv, j + 1), s2i = __shfl(sv, j + 2), s3i = __shfl(sv, j + 3);
        float w0 = __shfl(wv, j), w1i = __shfl(wv, j + 1), w2i = __shfl(wv, j + 2), w3i = __shfl(wv, j + 3);
        u32 d0 = cmsg32[(size_t)s0 * 64 + lane];
        u32 d1 = cmsg32[(size_t)s1i * 64 + lane];
        u32 d2 = cmsg32[(size_t)s2i * 64 + lane];
        u32 d3 = cmsg32[(size_t)s3i * 64 + lane];
        float f0, f1;
        unp2(d0, f0, f1); a0 = fmaf(w0, f0, a0); a1 = fmaf(w0, f1, a1);
        unp2(d1, f0, f1); a0 = fmaf(w1i, f0, a0); a1 = fmaf(w1i, f1, a1);
        unp2(d2, f0, f1); a0 = fmaf(w2i, f0, a0); a1 = fmaf(w2i, f1, a1);
        unp2(d3, f0, f1); a0 = fmaf(w3i, f0, a0); a1 = fmaf(w3i, f1, a1);
      }
      for (; j < m; ++j) {
        int sj = __shfl(sv, j); float wj = __shfl(wv, j);
        u32 d = cmsg32[(size_t)sj * 64 + lane];
        float f0, f1; unp2(d, f0, f1);
        a0 = fmaf(wj, f0, a0); a1 = fmaf(wj, f1, a1);
      }
    }
    lagg32[(size_t)seg * 64 + lane] = pk2(a0, a1);
  }
}

// ---------- phase 4: literal update GEMM, K=384, LDS-free direct-A ----------
__global__ __launch_bounds__(256) void k_updL(
    const u16* __restrict__ cl_bf, const u16* __restrict__ lagg, const u16* __restrict__ lmsg2,
    const u16* __restrict__ pW, const float* __restrict__ bias,
    float* __restrict__ ob, u16* __restrict__ ob_bf, int n)
{
  const int tid = threadIdx.x;
  const int lane = tid & 63;
  const int w = tid >> 6;
  const int r0 = blockIdx.x * 64;
  const int arow = r0 + w * 16 + (lane & 15);
  const int kgrp = (lane >> 4) * 8;
  const int dcol = lane & 15;
  const int drow0 = w * 16 + (lane >> 4) * 4;
  const bool ok = arow < n;
  f4v acc[8];
#pragma unroll
  for (int nt = 0; nt < 8; ++nt) {
    float bv = bias[nt * 16 + dcol];
    acc[nt] = (f4v){bv, bv, bv, bv};
  }
#pragma unroll
  for (int kc = 0; kc < 12; ++kc) {
    int col = kc * 32 + kgrp;
    s8v a = {0, 0, 0, 0, 0, 0, 0, 0};
    if (ok) {
      if (kc < 4)      a = *(const s8v*)(cl_bf + (size_t)arow * 128 + col);
      else if (kc < 8) a = *(const s8v*)(lagg + (size_t)arow * 128 + (col - 128));
      else             a = *(const s8v*)(lmsg2 + (size_t)(arow ^ 1) * 128 + (col - 256));
    }
#pragma unroll
    for (int nt = 0; nt < 8; ++nt) {
      s8v b = *(const s8v*)(pW + ((size_t)(kc * 8 + nt) * 64 + lane) * 8);
      acc[nt] = __builtin_amdgcn_mfma_f32_16x16x32_bf16(a, b, acc[nt], 0, 0, 0);
    }
  }
#pragma unroll
  for (int nt = 0; nt < 8; ++nt)
#pragma unroll
    for (int r = 0; r < 4; ++r) {
      int gr = r0 + drow0 + r;
      if (gr < n) {
        float v = acc[nt][r];
        ob[(size_t)gr * 128 + nt * 16 + dcol] = v;
        ob_bf[(size_t)gr * 128 + nt * 16 + dcol] = f2bf(v);
      }
    }
}

// ---------- host launch ----------
extern "C" void kernel_launch(void* const* d_in, const int* in_sizes, int n_in,
                              void* d_out, int out_size, void* d_ws, size_t ws_size,
                              hipStream_t stream)
{
  const float* l_emb0  = (const float*)d_in[0];
  const float* c_emb0  = (const float*)d_in[1];
  const float* l2c_W   = (const float*)d_in[2];
  const float* l2c_b   = (const float*)d_in[3];
  const float* c2l_W   = (const float*)d_in[4];
  const float* c2l_b   = (const float*)d_in[5];
  const float* l2l_W   = (const float*)d_in[6];
  const float* l2l_b   = (const float*)d_in[7];
  const float* c_att   = (const float*)d_in[8];
  const float* l_att   = (const float*)d_in[9];
  const float* c_upd_W = (const float*)d_in[10];
  const float* c_upd_b = (const float*)d_in[11];
  const float* l_upd_W = (const float*)d_in[12];
  const float* l_upd_b = (const float*)d_in[13];
  const int* l_edge    = (const int*)d_in[14];
  const int* c_edge    = (const int*)d_in[15];

  const int L = in_sizes[0] / 128;
  const int C = in_sizes[1] / 128;
  const int E = in_sizes[14];

  float* out_l = (float*)d_out;                    // [5][L][128] f32
  float* out_c = out_l + (size_t)5 * L * 128;      // [5][C][128] f32

  char* wsb = (char*)d_ws;
  size_t off = 0;
  auto alloc = [&](size_t bytes) -> char* {
    char* p = wsb + off;
    off = (off + bytes + 255) & ~(size_t)255;
    return p;
  };
  u16* lbuf  = (u16*)alloc((size_t)L * 128 * 2);
  u16* lmsg2 = (u16*)alloc((size_t)L * 128 * 2);
  u16* cmsg  = (u16*)alloc((size_t)C * 128 * 2);
  u16* lagg  = (u16*)alloc((size_t)L * 128 * 2);
  u16* cagg  = (u16*)alloc((size_t)C * 128 * 2);
  u16* cl_bf = (u16*)alloc((size_t)L * 128 * 2);
  u16* cc_bf = (u16*)alloc((size_t)C * 128 * 2);
  float* lab = (float*)alloc((size_t)L * 8);       // interleaved (lb, la)
  float* ca  = (float*)alloc((size_t)C * 4);
  float* cb  = (float*)alloc((size_t)C * 4);
  float* w2p = (float*)alloc((size_t)E * 4);
  int* c_off_a = (int*)alloc((size_t)(C + 1) * 4);
  int* l_off_a = (int*)alloc((size_t)(L + 1) * 4);
  int* l_src   = (int*)alloc((size_t)E * 4);
  int* l_posmap= (int*)alloc((size_t)E * 4);
  int* c_src   = (int*)alloc((size_t)E * 4);
  int* c_lpos  = (int*)alloc((size_t)E * 4);
  int* cntL    = (int*)alloc((size_t)L * 4);
  int* cntC    = (int*)alloc((size_t)C * 4);
  int* bsums   = (int*)alloc((size_t)(2 * SCAN_B) * 4);
  const int PACK_TOTAL = 4 * 180224;
  u16* packW   = (u16*)alloc((size_t)PACK_TOTAL * 2);
  (void)ws_size; (void)n_in; (void)out_size;

  // slice 0 + bf16 shadows + zero CSR counters (one dispatch)
  k_init2<<<2048, 256, 0, stream>>>(l_emb0, out_l, cl_bf, c_emb0, out_c, cc_bf,
                                    L * 128, C * 128, cntL, L, cntC, C);
  // weight repack
  k_packW<<<(PACK_TOTAL + 255) / 256, 256, 0, stream>>>(l2c_W, c2l_W, l2l_W, c_upd_W, l_upd_W,
                                                        packW, PACK_TOTAL);
  // CSR build (scanB folded into scanC)
  k_hist2<<<1024, 256, 0, stream>>>(l_edge, cntL, c_edge, cntC, E);
  k_scanA<<<2 * SCAN_B, 256, 0, stream>>>(cntL, L, cntC, C, bsums);
  k_scanC<<<2 * SCAN_B, 256, 0, stream>>>(cntL, l_off_a, L, cntC, c_off_a, C, bsums);
  k_fill_l<<<1024, 256, 0, stream>>>(l_edge, c_edge, cntL, l_src, l_posmap, E);
  k_fill_c<<<1024, 256, 0, stream>>>(l_edge, c_edge, l_posmap, cntC, c_src, c_lpos, E);

  const int NBL = (L + 63) / 64;
  const int NBC = (C + 63) / 64;
  const int UBC = (C + 63) / 64;
  const int ABL = (L + 3) / 4;
  const size_t PI = 180224;
  for (int i = 0; i < 4; ++i) {
    float* OLn = out_l + (size_t)(i + 1) * L * 128;
    float* OCn = out_c + (size_t)(i + 1) * C * 128;

    const u16* pl2c0 = packW + i * PI;
    const u16* pl2c1 = packW + i * PI + 16384;
    const u16* pc2l0 = packW + i * PI + 32768;
    const u16* pc2l1 = packW + i * PI + 49152;
    const u16* pl2l0 = packW + i * PI + 65536;
    const u16* pl2l1 = packW + i * PI + 81920;
    const u16* pcupd = packW + i * PI + 98304;
    const u16* plupd = packW + i * PI + 131072;

    const float* b0l = l2c_b + (size_t)i * 2 * 128;
    const float* b0c = c2l_b + (size_t)i * 2 * 128;
    const float* b0x = l2l_b + (size_t)i * 2 * 128;

    // phase 1: l2c + l2l + c2l MLPs + 4 attention dots (staging-free, barrier-free)
    k_phase1<<<NBL + NBC, 256, 0, stream>>>(
        cl_bf, cc_bf,
        pl2c0, b0l, pl2c1, b0l + 128,
        pl2l0, b0x, pl2l1, b0x + 128,
        lbuf, lmsg2,
        l_att + (size_t)i * 256, c_att + (size_t)i * 256 + 128, lab,
        pc2l0, b0c, pc2l1, b0c + 128, cmsg,
        c_att + (size_t)i * 256, l_att + (size_t)i * 256 + 128, ca, cb,
        L, C, NBL);

    // phase 2: softmax + clause aggregation; emits w2p
    k_att_aggrC<<<(C + 3) / 4, 256, 0, stream>>>(
        c_off_a, c_src, c_lpos, ca, cb, (const float2*)lab, w2p,
        (const u32*)lbuf, (u32*)cagg, C);

    // phase 3: clause update GEMM || literal aggregation
    k_phase3<<<UBC + ABL, 256, 0, stream>>>(
        cc_bf, cagg, pcupd, c_upd_b + (size_t)i * 128, OCn, cc_bf, C, UBC,
        l_off_a, w2p, l_src, (const u32*)cmsg, (u32*)lagg, L);

    // phase 4: literal update GEMM (LDS-free)
    k_updL<<<NBL, 256, 0, stream>>>(
        cl_bf, lagg, lmsg2, plupd, l_upd_b + (size_t)i * 128, OLn, cl_bf, L);
  }
}

// Round 15
// 1086.072 us; speedup vs baseline: 1.0873x; 1.0873x over previous
//
#include <hip/hip_runtime.h>

typedef unsigned short u16;
typedef unsigned int u32;
typedef __attribute__((ext_vector_type(8))) short s8v;   // 8 bf16 = 4 VGPR
typedef __attribute__((ext_vector_type(4))) float f4v;   // MFMA accum

#define SCAN_B 240

// ---------- bf16 helpers ----------
__device__ __forceinline__ u16 f2bf(float f) {
  u32 u = __float_as_uint(f);
  u += 0x7FFFu + ((u >> 16) & 1u);
  return (u16)(u >> 16);
}
__device__ __forceinline__ void unp2(u32 u, float& a, float& b) {
  a = __uint_as_float(u << 16);
  b = __uint_as_float(u & 0xFFFF0000u);
}
__device__ __forceinline__ u32 pk2(float a, float b) {
  return (u32)f2bf(a) | ((u32)f2bf(b) << 16);
}

// ---------- init: f32 copy + bf16 shadow + zero CSR counters, one dispatch ----------
__global__ void k_init2(const float* __restrict__ lsrc, float* __restrict__ ld32,
                        u16* __restrict__ ldbf,
                        const float* __restrict__ csrc, float* __restrict__ cd32,
                        u16* __restrict__ cdbf, int nl, int nc,
                        int* __restrict__ cntL, int nzL, int* __restrict__ cntC, int nzC) {
  int i = blockIdx.x * blockDim.x + threadIdx.x, st = gridDim.x * blockDim.x;
  int tot = nl + nc + nzL + nzC;
  for (; i < tot; i += st) {
    if (i < nl) { float v = lsrc[i]; ld32[i] = v; ldbf[i] = f2bf(v); }
    else if (i < nl + nc) { int j = i - nl; float v = csrc[j]; cd32[j] = v; cdbf[j] = f2bf(v); }
    else if (i < nl + nc + nzL) cntL[i - nl - nc] = 0;
    else cntC[i - nl - nc - nzL] = 0;
  }
}

// ---------- CSR build ----------
__global__ void k_hist2(const int* __restrict__ l_edge, int* __restrict__ cntL,
                        const int* __restrict__ c_edge, int* __restrict__ cntC, int ne) {
  int i = blockIdx.x * blockDim.x + threadIdx.x, s = gridDim.x * blockDim.x;
  for (; i < 2 * ne; i += s) {
    if (i < ne) atomicAdd(&cntL[l_edge[i]], 1);
    else atomicAdd(&cntC[c_edge[i - ne]], 1);
  }
}
__global__ __launch_bounds__(256) void k_scanA(const int* __restrict__ cntL, int nL,
                                               const int* __restrict__ cntC, int nC,
                                               int* __restrict__ bsums) {
  const bool isL = (int)blockIdx.x < SCAN_B;
  const int* cnt = isL ? cntL : cntC;
  const int n = isL ? nL : nC;
  const int b = isL ? blockIdx.x : blockIdx.x - SCAN_B;
  const int chunk = (n + SCAN_B - 1) / SCAN_B;
  const int s0 = b * chunk;
  int s1 = s0 + chunk; if (s1 > n) s1 = n;
  int s = 0;
  for (int i = s0 + (int)threadIdx.x; i < s1; i += 256) s += cnt[i];
  __shared__ int red[256];
  red[threadIdx.x] = s; __syncthreads();
  for (int d = 128; d >= 1; d >>= 1) {
    if ((int)threadIdx.x < d) red[threadIdx.x] += red[threadIdx.x + d];
    __syncthreads();
  }
  if (threadIdx.x == 0) bsums[blockIdx.x] = red[0];
}
// scanC with folded block-sum scan (replaces the former k_scanB dispatch)
__global__ __launch_bounds__(256) void k_scanC(int* __restrict__ cntL, int* __restrict__ offL, int nL,
                                               int* __restrict__ cntC, int* __restrict__ offC, int nC,
                                               const int* __restrict__ bsums) {
  const bool isL = (int)blockIdx.x < SCAN_B;
  int* cnt = isL ? cntL : cntC;
  int* offs = isL ? offL : offC;
  const int n = isL ? nL : nC;
  const int b = isL ? blockIdx.x : blockIdx.x - SCAN_B;
  const int* bs = bsums + (isL ? 0 : SCAN_B);
  const int t = threadIdx.x;
  __shared__ int shb[256];
  int bv = (t < SCAN_B) ? bs[t] : 0;
  shb[t] = bv; __syncthreads();
  for (int d = 1; d < 256; d <<= 1) {
    int x = (t >= d) ? shb[t - d] : 0;
    __syncthreads();
    shb[t] += x;
    __syncthreads();
  }
  int run = (b == 0) ? 0 : shb[b - 1];
  const int total = shb[255];
  const int chunk = (n + SCAN_B - 1) / SCAN_B;
  const int s0 = b * chunk;
  int s1 = s0 + chunk; if (s1 > n) s1 = n;
  __shared__ int sh[256];
  for (int t0 = s0; t0 < s1; t0 += 256) {
    int i = t0 + t;
    int v = (i < s1) ? cnt[i] : 0;
    sh[t] = v; __syncthreads();
    for (int d = 1; d < 256; d <<= 1) {
      int x = (t >= d) ? sh[t - d] : 0;
      __syncthreads();
      sh[t] += x;
      __syncthreads();
    }
    int incl = sh[t];
    if (i < s1) { int e = run + incl - v; offs[i] = e; cnt[i] = e; }
    int tilesum = sh[255];
    __syncthreads();
    run += tilesum;
  }
  if (b == 0 && t == 0) offs[n] = total;
}
__global__ void k_fill_l(const int* __restrict__ l_edge, const int* __restrict__ c_edge,
                         int* __restrict__ cursor, int* __restrict__ l_src,
                         int* __restrict__ l_posmap, int ne) {
  int i = blockIdx.x * blockDim.x + threadIdx.x, s = gridDim.x * blockDim.x;
  for (; i < ne; i += s) {
    int pos = atomicAdd(&cursor[l_edge[i]], 1);
    l_src[pos] = c_edge[i];
    l_posmap[i] = pos;
  }
}
__global__ void k_fill_c(const int* __restrict__ l_edge, const int* __restrict__ c_edge,
                         const int* __restrict__ l_posmap,
                         int* __restrict__ cursor, int* __restrict__ c_src,
                         int* __restrict__ c_lpos, int ne) {
  int i = blockIdx.x * blockDim.x + threadIdx.x, s = gridDim.x * blockDim.x;
  for (; i < ne; i += s) {
    int pos = atomicAdd(&cursor[c_edge[i]], 1);
    c_src[pos] = l_edge[i];
    c_lpos[pos] = l_posmap[i];
  }
}

// ---------- weight repack: f32 [K][128] -> bf16 MFMA B-frag layout ----------
__global__ void k_packW(const float* __restrict__ l2c_W, const float* __restrict__ c2l_W,
                        const float* __restrict__ l2l_W, const float* __restrict__ c_upd_W,
                        const float* __restrict__ l_upd_W, u16* __restrict__ dst, int total) {
  int o = blockIdx.x * blockDim.x + threadIdx.x;
  if (o >= total) return;
  int it = o / 180224;
  int r = o - it * 180224;
  const float* src;
  int o2;
  if (r < 98304) {
    int m = r >> 14;           // 0..5
    o2 = r & 16383;
    if (m < 2)      src = l2c_W + ((size_t)it * 2 + m) * 16384;
    else if (m < 4) src = c2l_W + ((size_t)it * 2 + (m - 2)) * 16384;
    else            src = l2l_W + ((size_t)it * 2 + (m - 4)) * 16384;
  } else if (r < 131072) {
    o2 = r - 98304;  src = c_upd_W + (size_t)it * 32768;
  } else {
    o2 = r - 131072; src = l_upd_W + (size_t)it * 49152;
  }
  int j = o2 & 7, lane = (o2 >> 3) & 63, f = o2 >> 9;
  int nt = f & 7, kc = f >> 3;
  int k = kc * 32 + ((lane >> 4) << 3) + j;
  int nn = nt * 16 + (lane & 15);
  dst[o] = f2bf(src[(size_t)k * 128 + nn]);
}

// ---------- phase 1: merged L-side dual-MLP + C-side MLP (+ fused dots) ----------
// L-side dots interleaved into lab[gr] = (x-dot, y-dot); C-side: plain ca/cb.
__global__ __launch_bounds__(256) void k_phase1(
    const u16* __restrict__ cl_bf, const u16* __restrict__ cc_bf,
    const u16* __restrict__ pl2c0, const float* __restrict__ bl0,
    const u16* __restrict__ pl2c1, const float* __restrict__ bl1,
    const u16* __restrict__ pl2l0, const float* __restrict__ bx0,
    const u16* __restrict__ pl2l1, const float* __restrict__ bx1,
    u16* __restrict__ lbuf, u16* __restrict__ lmsg2,
    const float* __restrict__ lattA, const float* __restrict__ cattB,
    float* __restrict__ lab,
    const u16* __restrict__ pc2l0, const float* __restrict__ bc0,
    const u16* __restrict__ pc2l1, const float* __restrict__ bc1,
    u16* __restrict__ cmsg,
    const float* __restrict__ cattA, const float* __restrict__ lattB,
    float* __restrict__ ca, float* __restrict__ cb,
    int L, int C, int NBL)
{
  __shared__ u16 xs[64][136];
  __shared__ u16 hs[64][136];
  const int tid = threadIdx.x;
  const int lane = tid & 63;
  const int w = tid >> 6;
  const bool isL = (int)blockIdx.x < NBL;
  const int r0 = (isL ? blockIdx.x : blockIdx.x - NBL) * 64;
  const int n = isL ? L : C;
  const u16* x_bf = isL ? cl_bf : cc_bf;
  const u16* pW0 = isL ? pl2c0 : pc2l0;
  const float* b0 = isL ? bl0 : bc0;
  const u16* pW1 = isL ? pl2c1 : pc2l1;
  const float* b1 = isL ? bl1 : bc1;
  u16* y = isL ? lbuf : cmsg;
  const float* attx = isL ? lattA : cattA;
  const float* atty = isL ? cattB : lattB;
  float* dx = isL ? lab : ca;        // x-dot target
  float* dy = isL ? lab + 1 : cb;    // y-dot target
  const int dstr = isL ? 2 : 1;

  for (int t = tid; t < 64 * 16; t += 256) {
    int row = t >> 4, ch = t & 15; int gr = r0 + row;
    uint4 v = make_uint4(0, 0, 0, 0);
    if (gr < n) v = *(const uint4*)(x_bf + (size_t)gr * 128 + ch * 8);
    *(uint4*)&xs[row][ch * 8] = v;
  }
  __syncthreads();

  // fused x-dot
  {
    float2 ax = *(const float2*)(attx + lane * 2);
    for (int r = 0; r < 16; ++r) {
      int row = w * 16 + r; int gr = r0 + row;
      u32 v = *(const u32*)&xs[row][lane * 2];
      float f0, f1; unp2(v, f0, f1);
      float p = f0 * ax.x + f1 * ax.y;
#pragma unroll
      for (int d = 32; d >= 1; d >>= 1) p += __shfl_xor(p, d);
      if (lane == 0 && gr < n) dx[(size_t)gr * dstr] = p;
    }
  }

  const int arow = w * 16 + (lane & 15);
  const int kgrp = (lane >> 4) * 8;
  const int dcol = lane & 15;
  const int drow0 = w * 16 + (lane >> 4) * 4;
  f4v acc[8];

  // ----- MLP1 -----
#pragma unroll
  for (int nt = 0; nt < 8; ++nt) {
    float bv = b0[nt * 16 + dcol];
    acc[nt] = (f4v){bv, bv, bv, bv};
  }
#pragma unroll
  for (int kc = 0; kc < 4; ++kc) {
    s8v a = *(const s8v*)&xs[arow][kc * 32 + kgrp];
#pragma unroll
    for (int nt = 0; nt < 8; ++nt) {
      s8v b = *(const s8v*)(pW0 + ((size_t)(kc * 8 + nt) * 64 + lane) * 8);
      acc[nt] = __builtin_amdgcn_mfma_f32_16x16x32_bf16(a, b, acc[nt], 0, 0, 0);
    }
  }
#pragma unroll
  for (int nt = 0; nt < 8; ++nt)
#pragma unroll
    for (int r = 0; r < 4; ++r)
      hs[drow0 + r][nt * 16 + dcol] = f2bf(fmaxf(acc[nt][r], 0.f));
  __syncthreads();
#pragma unroll
  for (int nt = 0; nt < 8; ++nt) {
    float bv = b1[nt * 16 + dcol];
    acc[nt] = (f4v){bv, bv, bv, bv};
  }
#pragma unroll
  for (int kc = 0; kc < 4; ++kc) {
    s8v a = *(const s8v*)&hs[arow][kc * 32 + kgrp];
#pragma unroll
    for (int nt = 0; nt < 8; ++nt) {
      s8v b = *(const s8v*)(pW1 + ((size_t)(kc * 8 + nt) * 64 + lane) * 8);
      acc[nt] = __builtin_amdgcn_mfma_f32_16x16x32_bf16(a, b, acc[nt], 0, 0, 0);
    }
  }
#pragma unroll
  for (int nt = 0; nt < 8; ++nt)
#pragma unroll
    for (int r = 0; r < 4; ++r) {
      int gr = r0 + drow0 + r;
      if (gr < n) y[(size_t)gr * 128 + nt * 16 + dcol] = f2bf(acc[nt][r]);
    }
  // fused y-dot
  {
    float pr[4] = {0.f, 0.f, 0.f, 0.f};
#pragma unroll
    for (int nt = 0; nt < 8; ++nt) {
      float av = atty[nt * 16 + dcol];
#pragma unroll
      for (int r = 0; r < 4; ++r) pr[r] = fmaf(acc[nt][r], av, pr[r]);
    }
#pragma unroll
    for (int d = 8; d >= 1; d >>= 1)
#pragma unroll
      for (int r = 0; r < 4; ++r) pr[r] += __shfl_xor(pr[r], d);
    if ((lane & 15) == 0) {
#pragma unroll
      for (int r = 0; r < 4; ++r) {
        int gr = r0 + drow0 + r;
        if (gr < n) dy[(size_t)gr * dstr] = pr[r];
      }
    }
  }

  // ----- MLP2 (L-side only, shares xs) -----
  if (isL) {
    __syncthreads();
#pragma unroll
    for (int nt = 0; nt < 8; ++nt) {
      float bv = bx0[nt * 16 + dcol];
      acc[nt] = (f4v){bv, bv, bv, bv};
    }
#pragma unroll
    for (int kc = 0; kc < 4; ++kc) {
      s8v a = *(const s8v*)&xs[arow][kc * 32 + kgrp];
#pragma unroll
      for (int nt = 0; nt < 8; ++nt) {
        s8v b = *(const s8v*)(pl2l0 + ((size_t)(kc * 8 + nt) * 64 + lane) * 8);
        acc[nt] = __builtin_amdgcn_mfma_f32_16x16x32_bf16(a, b, acc[nt], 0, 0, 0);
      }
    }
#pragma unroll
    for (int nt = 0; nt < 8; ++nt)
#pragma unroll
      for (int r = 0; r < 4; ++r)
        hs[drow0 + r][nt * 16 + dcol] = f2bf(fmaxf(acc[nt][r], 0.f));
    __syncthreads();
#pragma unroll
    for (int nt = 0; nt < 8; ++nt) {
      float bv = bx1[nt * 16 + dcol];
      acc[nt] = (f4v){bv, bv, bv, bv};
    }
#pragma unroll
    for (int kc = 0; kc < 4; ++kc) {
      s8v a = *(const s8v*)&hs[arow][kc * 32 + kgrp];
#pragma unroll
      for (int nt = 0; nt < 8; ++nt) {
        s8v b = *(const s8v*)(pl2l1 + ((size_t)(kc * 8 + nt) * 64 + lane) * 8);
        acc[nt] = __builtin_amdgcn_mfma_f32_16x16x32_bf16(a, b, acc[nt], 0, 0, 0);
      }
    }
#pragma unroll
    for (int nt = 0; nt < 8; ++nt)
#pragma unroll
      for (int r = 0; r < 4; ++r) {
        int gr = r0 + drow0 + r;
        if (gr < n) lmsg2[(size_t)gr * 128 + nt * 16 + dcol] = f2bf(acc[nt][r]);
      }
  }
}

// ---------- phase 2: fused softmax + clause aggregation (wave per clause) ----------
__global__ __launch_bounds__(256) void k_att_aggrC(
    const int* __restrict__ c_off, const int* __restrict__ c_src, const int* __restrict__ c_lpos,
    const float* __restrict__ ca, const float* __restrict__ cb,
    const float2* __restrict__ lab,
    float* __restrict__ w2p,
    const u32* __restrict__ feat32, u32* __restrict__ out32, int C)
{
  const int lane = threadIdx.x & 63;
  const int gid = blockIdx.x * 4 + (threadIdx.x >> 6);
  if (gid >= C) return;
  const int off = c_off[gid];
  const int deg = c_off[gid + 1] - off;
  float a0 = 0.f, a1 = 0.f;
  if (deg > 0 && deg <= 64) {
    const float cav = ca[gid], cbv = cb[gid];
    bool on = lane < deg;
    int sv = 0, lp = 0;
    float s1 = -3.0e38f, s2 = -3.0e38f;
    if (on) {
      sv = c_src[off + lane];
      lp = c_lpos[off + lane];
      float2 v = lab[sv];            // .x = lb (x-dot), .y = la (y-dot)
      s1 = cav + v.y; s1 = s1 > 0.f ? s1 : 0.2f * s1;
      s2 = v.x + cbv; s2 = s2 > 0.f ? s2 : 0.2f * s2;
    }
    float m1 = s1, m2 = s2;
#pragma unroll
    for (int d = 32; d >= 1; d >>= 1) {
      m1 = fmaxf(m1, __shfl_xor(m1, d));
      m2 = fmaxf(m2, __shfl_xor(m2, d));
    }
    float e1 = on ? __expf(s1 - m1) : 0.f;
    float e2 = on ? __expf(s2 - m2) : 0.f;
    float z1 = e1, z2 = e2;
#pragma unroll
    for (int d = 32; d >= 1; d >>= 1) {
      z1 += __shfl_xor(z1, d);
      z2 += __shfl_xor(z2, d);
    }
    float wv = on ? e1 / (z1 + 1e-16f) : 0.f;
    if (on) w2p[lp] = e2 / (z2 + 1e-16f);
    int j = 0;
    for (; j + 4 <= deg; j += 4) {
      int s0 = __shfl(sv, j), s1i = __shfl(sv, j + 1), s2i = __shfl(sv, j + 2), s3i = __shfl(sv, j + 3);
      float w0 = __shfl(wv, j), w1i = __shfl(wv, j + 1), w2i = __shfl(wv, j + 2), w3i = __shfl(wv, j + 3);
      u32 d0 = feat32[(size_t)s0 * 64 + lane];
      u32 d1 = feat32[(size_t)s1i * 64 + lane];
      u32 d2 = feat32[(size_t)s2i * 64 + lane];
      u32 d3 = feat32[(size_t)s3i * 64 + lane];
      float f0, f1;
      unp2(d0, f0, f1); a0 = fmaf(w0, f0, a0); a1 = fmaf(w0, f1, a1);
      unp2(d1, f0, f1); a0 = fmaf(w1i, f0, a0); a1 = fmaf(w1i, f1, a1);
      unp2(d2, f0, f1); a0 = fmaf(w2i, f0, a0); a1 = fmaf(w2i, f1, a1);
      unp2(d3, f0, f1); a0 = fmaf(w3i, f0, a0); a1 = fmaf(w3i, f1, a1);
    }
    for (; j < deg; ++j) {
      int sj = __shfl(sv, j); float wj = __shfl(wv, j);
      u32 d = feat32[(size_t)sj * 64 + lane];
      float f0, f1; unp2(d, f0, f1);
      a0 = fmaf(wj, f0, a0); a1 = fmaf(wj, f1, a1);
    }
  } else if (deg > 64) {
    const float cav = ca[gid], cbv = cb[gid];
    float m1 = -3.0e38f, m2 = -3.0e38f;
    for (int base = 0; base < deg; base += 64) {
      int idx = base + lane;
      if (idx < deg) {
        float2 v = lab[c_src[off + idx]];
        float s1 = cav + v.y; s1 = s1 > 0.f ? s1 : 0.2f * s1;
        float s2 = v.x + cbv; s2 = s2 > 0.f ? s2 : 0.2f * s2;
        m1 = fmaxf(m1, s1); m2 = fmaxf(m2, s2);
      }
    }
#pragma unroll
    for (int d = 32; d >= 1; d >>= 1) {
      m1 = fmaxf(m1, __shfl_xor(m1, d));
      m2 = fmaxf(m2, __shfl_xor(m2, d));
    }
    float z1 = 0.f, z2 = 0.f;
    for (int base = 0; base < deg; base += 64) {
      int idx = base + lane;
      if (idx < deg) {
        float2 v = lab[c_src[off + idx]];
        float s1 = cav + v.y; s1 = s1 > 0.f ? s1 : 0.2f * s1;
        float s2 = v.x + cbv; s2 = s2 > 0.f ? s2 : 0.2f * s2;
        z1 += __expf(s1 - m1); z2 += __expf(s2 - m2);
      }
    }
#pragma unroll
    for (int d = 32; d >= 1; d >>= 1) { z1 += __shfl_xor(z1, d); z2 += __shfl_xor(z2, d); }
    float i1 = 1.f / (z1 + 1e-16f), i2 = 1.f / (z2 + 1e-16f);
    for (int base = 0; base < deg; base += 64) {
      int m = deg - base; if (m > 64) m = 64;
      int sv = 0; float wv = 0.f;
      if (lane < m) {
        int idx = base + lane;
        sv = c_src[off + idx];
        float2 v = lab[sv];
        float s1 = cav + v.y; s1 = s1 > 0.f ? s1 : 0.2f * s1;
        float s2 = v.x + cbv; s2 = s2 > 0.f ? s2 : 0.2f * s2;
        wv = __expf(s1 - m1) * i1;
        w2p[c_lpos[off + idx]] = __expf(s2 - m2) * i2;
      }
      for (int j = 0; j < m; ++j) {
        int sj = __shfl(sv, j); float wj = __shfl(wv, j);
        u32 d = feat32[(size_t)sj * 64 + lane];
        float f0, f1; unp2(d, f0, f1);
        a0 = fmaf(wj, f0, a0); a1 = fmaf(wj, f1, a1);
      }
    }
  }
  out32[(size_t)gid * 64 + lane] = pk2(a0, a1);
}

// ---------- phase 3: merged clause update GEMM (LDS-free) + literal aggregation ----------
__global__ __launch_bounds__(256) void k_phase3(
    const u16* __restrict__ cc_bf, const u16* __restrict__ cagg,
    const u16* __restrict__ pWc, const float* __restrict__ biasC,
    float* __restrict__ obC, u16* __restrict__ obC_bf, int C, int UBC,
    const int* __restrict__ l_off, const float* __restrict__ w2p,
    const int* __restrict__ l_src,
    const u32* __restrict__ cmsg32, u32* __restrict__ lagg32, int L)
{
  const int tid = threadIdx.x;
  const int lane = tid & 63;
  const int w = tid >> 6;
  if ((int)blockIdx.x < UBC) {
    const int r0 = blockIdx.x * 64;
    const int arow = r0 + w * 16 + (lane & 15);
    const int kgrp = (lane >> 4) * 8;
    const int dcol = lane & 15;
    const int drow0 = w * 16 + (lane >> 4) * 4;
    const bool ok = arow < C;
    f4v acc[8];
#pragma unroll
    for (int nt = 0; nt < 8; ++nt) {
      float bv = biasC[nt * 16 + dcol];
      acc[nt] = (f4v){bv, bv, bv, bv};
    }
#pragma unroll
    for (int kc = 0; kc < 8; ++kc) {
      int col = kc * 32 + kgrp;
      s8v a = {0, 0, 0, 0, 0, 0, 0, 0};
      if (ok) {
        if (kc < 4) a = *(const s8v*)(cc_bf + (size_t)arow * 128 + col);
        else        a = *(const s8v*)(cagg + (size_t)arow * 128 + (col - 128));
      }
#pragma unroll
      for (int nt = 0; nt < 8; ++nt) {
        s8v b = *(const s8v*)(pWc + ((size_t)(kc * 8 + nt) * 64 + lane) * 8);
        acc[nt] = __builtin_amdgcn_mfma_f32_16x16x32_bf16(a, b, acc[nt], 0, 0, 0);
      }
    }
#pragma unroll
    for (int nt = 0; nt < 8; ++nt)
#pragma unroll
      for (int r = 0; r < 4; ++r) {
        int gr = r0 + drow0 + r;
        if (gr < C) {
          float v = acc[nt][r];
          obC[(size_t)gr * 128 + nt * 16 + dcol] = v;
          obC_bf[(size_t)gr * 128 + nt * 16 + dcol] = f2bf(v);
        }
      }
  } else {
    const int seg = (blockIdx.x - UBC) * 4 + w;
    if (seg >= L) return;
    const int off = l_off[seg];
    const int deg = l_off[seg + 1] - off;
    float a0 = 0.f, a1 = 0.f;
    for (int base = 0; base < deg; base += 64) {
      int m = deg - base; if (m > 64) m = 64;
      float wv = 0.f; int sv = 0;
      if (lane < m) { wv = w2p[off + base + lane]; sv = l_src[off + base + lane]; }
      int j = 0;
      for (; j + 4 <= m; j += 4) {
        int s0 = __shfl(sv, j), s1i = __shfl(sv, j + 1), s2i = __shfl(sv, j + 2), s3i = __shfl(sv, j + 3);
        float w0 = __shfl(wv, j), w1i = __shfl(wv, j + 1), w2i = __shfl(wv, j + 2), w3i = __shfl(wv, j + 3);
        u32 d0 = cmsg32[(size_t)s0 * 64 + lane];
        u32 d1 = cmsg32[(size_t)s1i * 64 + lane];
        u32 d2 = cmsg32[(size_t)s2i * 64 + lane];
        u32 d3 = cmsg32[(size_t)s3i * 64 + lane];
        float f0, f1;
        unp2(d0, f0, f1); a0 = fmaf(w0, f0, a0); a1 = fmaf(w0, f1, a1);
        unp2(d1, f0, f1); a0 = fmaf(w1i, f0, a0); a1 = fmaf(w1i, f1, a1);
        unp2(d2, f0, f1); a0 = fmaf(w2i, f0, a0); a1 = fmaf(w2i, f1, a1);
        unp2(d3, f0, f1); a0 = fmaf(w3i, f0, a0); a1 = fmaf(w3i, f1, a1);
      }
      for (; j < m; ++j) {
        int sj = __shfl(sv, j); float wj = __shfl(wv, j);
        u32 d = cmsg32[(size_t)sj * 64 + lane];
        float f0, f1; unp2(d, f0, f1);
        a0 = fmaf(wj, f0, a0); a1 = fmaf(wj, f1, a1);
      }
    }
    lagg32[(size_t)seg * 64 + lane] = pk2(a0, a1);
  }
}

// ---------- phase 4: literal update GEMM, K=384, LDS-free direct-A ----------
__global__ __launch_bounds__(256) void k_updL(
    const u16* __restrict__ cl_bf, const u16* __restrict__ lagg, const u16* __restrict__ lmsg2,
    const u16* __restrict__ pW, const float* __restrict__ bias,
    float* __restrict__ ob, u16* __restrict__ ob_bf, int n)
{
  const int tid = threadIdx.x;
  const int lane = tid & 63;
  const int w = tid >> 6;
  const int r0 = blockIdx.x * 64;
  const int arow = r0 + w * 16 + (lane & 15);
  const int kgrp = (lane >> 4) * 8;
  const int dcol = lane & 15;
  const int drow0 = w * 16 + (lane >> 4) * 4;
  const bool ok = arow < n;
  f4v acc[8];
#pragma unroll
  for (int nt = 0; nt < 8; ++nt) {
    float bv = bias[nt * 16 + dcol];
    acc[nt] = (f4v){bv, bv, bv, bv};
  }
#pragma unroll
  for (int kc = 0; kc < 12; ++kc) {
    int col = kc * 32 + kgrp;
    s8v a = {0, 0, 0, 0, 0, 0, 0, 0};
    if (ok) {
      if (kc < 4)      a = *(const s8v*)(cl_bf + (size_t)arow * 128 + col);
      else if (kc < 8) a = *(const s8v*)(lagg + (size_t)arow * 128 + (col - 128));
      else             a = *(const s8v*)(lmsg2 + (size_t)(arow ^ 1) * 128 + (col - 256));
    }
#pragma unroll
    for (int nt = 0; nt < 8; ++nt) {
      s8v b = *(const s8v*)(pW + ((size_t)(kc * 8 + nt) * 64 + lane) * 8);
      acc[nt] = __builtin_amdgcn_mfma_f32_16x16x32_bf16(a, b, acc[nt], 0, 0, 0);
    }
  }
#pragma unroll
  for (int nt = 0; nt < 8; ++nt)
#pragma unroll
    for (int r = 0; r < 4; ++r) {
      int gr = r0 + drow0 + r;
      if (gr < n) {
        float v = acc[nt][r];
        ob[(size_t)gr * 128 + nt * 16 + dcol] = v;
        ob_bf[(size_t)gr * 128 + nt * 16 + dcol] = f2bf(v);
      }
    }
}

// ---------- host launch ----------
extern "C" void kernel_launch(void* const* d_in, const int* in_sizes, int n_in,
                              void* d_out, int out_size, void* d_ws, size_t ws_size,
                              hipStream_t stream)
{
  const float* l_emb0  = (const float*)d_in[0];
  const float* c_emb0  = (const float*)d_in[1];
  const float* l2c_W   = (const float*)d_in[2];
  const float* l2c_b   = (const float*)d_in[3];
  const float* c2l_W   = (const float*)d_in[4];
  const float* c2l_b   = (const float*)d_in[5];
  const float* l2l_W   = (const float*)d_in[6];
  const float* l2l_b   = (const float*)d_in[7];
  const float* c_att   = (const float*)d_in[8];
  const float* l_att   = (const float*)d_in[9];
  const float* c_upd_W = (const float*)d_in[10];
  const float* c_upd_b = (const float*)d_in[11];
  const float* l_upd_W = (const float*)d_in[12];
  const float* l_upd_b = (const float*)d_in[13];
  const int* l_edge    = (const int*)d_in[14];
  const int* c_edge    = (const int*)d_in[15];

  const int L = in_sizes[0] / 128;
  const int C = in_sizes[1] / 128;
  const int E = in_sizes[14];

  float* out_l = (float*)d_out;                    // [5][L][128] f32
  float* out_c = out_l + (size_t)5 * L * 128;      // [5][C][128] f32

  char* wsb = (char*)d_ws;
  size_t off = 0;
  auto alloc = [&](size_t bytes) -> char* {
    char* p = wsb + off;
    off = (off + bytes + 255) & ~(size_t)255;
    return p;
  };
  u16* lbuf  = (u16*)alloc((size_t)L * 128 * 2);
  u16* lmsg2 = (u16*)alloc((size_t)L * 128 * 2);
  u16* cmsg  = (u16*)alloc((size_t)C * 128 * 2);
  u16* lagg  = (u16*)alloc((size_t)L * 128 * 2);
  u16* cagg  = (u16*)alloc((size_t)C * 128 * 2);
  u16* cl_bf = (u16*)alloc((size_t)L * 128 * 2);
  u16* cc_bf = (u16*)alloc((size_t)C * 128 * 2);
  float* lab = (float*)alloc((size_t)L * 8);       // interleaved (lb, la)
  float* ca  = (float*)alloc((size_t)C * 4);
  float* cb  = (float*)alloc((size_t)C * 4);
  float* w2p = (float*)alloc((size_t)E * 4);
  int* c_off_a = (int*)alloc((size_t)(C + 1) * 4);
  int* l_off_a = (int*)alloc((size_t)(L + 1) * 4);
  int* l_src   = (int*)alloc((size_t)E * 4);
  int* l_posmap= (int*)alloc((size_t)E * 4);
  int* c_src   = (int*)alloc((size_t)E * 4);
  int* c_lpos  = (int*)alloc((size_t)E * 4);
  int* cntL    = (int*)alloc((size_t)L * 4);
  int* cntC    = (int*)alloc((size_t)C * 4);
  int* bsums   = (int*)alloc((size_t)(2 * SCAN_B) * 4);
  const int PACK_TOTAL = 4 * 180224;
  u16* packW   = (u16*)alloc((size_t)PACK_TOTAL * 2);
  (void)ws_size; (void)n_in; (void)out_size;

  // slice 0 + bf16 shadows + zero CSR counters (one dispatch)
  k_init2<<<2048, 256, 0, stream>>>(l_emb0, out_l, cl_bf, c_emb0, out_c, cc_bf,
                                    L * 128, C * 128, cntL, L, cntC, C);
  // weight repack
  k_packW<<<(PACK_TOTAL + 255) / 256, 256, 0, stream>>>(l2c_W, c2l_W, l2l_W, c_upd_W, l_upd_W,
                                                        packW, PACK_TOTAL);
  // CSR build (scanB folded into scanC)
  k_hist2<<<1024, 256, 0, stream>>>(l_edge, cntL, c_edge, cntC, E);
  k_scanA<<<2 * SCAN_B, 256, 0, stream>>>(cntL, L, cntC, C, bsums);
  k_scanC<<<2 * SCAN_B, 256, 0, stream>>>(cntL, l_off_a, L, cntC, c_off_a, C, bsums);
  k_fill_l<<<1024, 256, 0, stream>>>(l_edge, c_edge, cntL, l_src, l_posmap, E);
  k_fill_c<<<1024, 256, 0, stream>>>(l_edge, c_edge, l_posmap, cntC, c_src, c_lpos, E);

  const int NBL = (L + 63) / 64;
  const int NBC = (C + 63) / 64;
  const int UBC = (C + 63) / 64;
  const int ABL = (L + 3) / 4;
  const size_t PI = 180224;
  for (int i = 0; i < 4; ++i) {
    float* OLn = out_l + (size_t)(i + 1) * L * 128;
    float* OCn = out_c + (size_t)(i + 1) * C * 128;

    const u16* pl2c0 = packW + i * PI;
    const u16* pl2c1 = packW + i * PI + 16384;
    const u16* pc2l0 = packW + i * PI + 32768;
    const u16* pc2l1 = packW + i * PI + 49152;
    const u16* pl2l0 = packW + i * PI + 65536;
    const u16* pl2l1 = packW + i * PI + 81920;
    const u16* pcupd = packW + i * PI + 98304;
    const u16* plupd = packW + i * PI + 131072;

    const float* b0l = l2c_b + (size_t)i * 2 * 128;
    const float* b0c = c2l_b + (size_t)i * 2 * 128;
    const float* b0x = l2l_b + (size_t)i * 2 * 128;

    // phase 1: l2c + l2l + c2l MLPs + 4 attention dots
    k_phase1<<<NBL + NBC, 256, 0, stream>>>(
        cl_bf, cc_bf,
        pl2c0, b0l, pl2c1, b0l + 128,
        pl2l0, b0x, pl2l1, b0x + 128,
        lbuf, lmsg2,
        l_att + (size_t)i * 256, c_att + (size_t)i * 256 + 128, lab,
        pc2l0, b0c, pc2l1, b0c + 128, cmsg,
        c_att + (size_t)i * 256, l_att + (size_t)i * 256 + 128, ca, cb,
        L, C, NBL);

    // phase 2: softmax + clause aggregation; emits w2p
    k_att_aggrC<<<(C + 3) / 4, 256, 0, stream>>>(
        c_off_a, c_src, c_lpos, ca, cb, (const float2*)lab, w2p,
        (const u32*)lbuf, (u32*)cagg, C);

    // phase 3: clause update GEMM || literal aggregation
    k_phase3<<<UBC + ABL, 256, 0, stream>>>(
        cc_bf, cagg, pcupd, c_upd_b + (size_t)i * 128, OCn, cc_bf, C, UBC,
        l_off_a, w2p, l_src, (const u32*)cmsg, (u32*)lagg, L);

    // phase 4: literal update GEMM (LDS-free)
    k_updL<<<NBL, 256, 0, stream>>>(
        cl_bf, lagg, lmsg2, plupd, l_upd_b + (size_t)i * 128, OLn, cl_bf, L);
  }
}